// Round 6
// baseline (328.859 us; speedup 1.0000x reference)
//
#include <hip/hip_runtime.h>

typedef unsigned short u16;
typedef __attribute__((ext_vector_type(8))) short bf16x8;
typedef __attribute__((ext_vector_type(8))) unsigned short u16x8;
typedef __attribute__((ext_vector_type(4))) float f32x4;

#define MFMA16(a, b, c) __builtin_amdgcn_mfma_f32_16x16x32_bf16(a, b, c, 0, 0, 0)

__device__ __forceinline__ u16 f2bf(float f) {
  union { float f; unsigned u; } v; v.f = f;
  unsigned r = v.u + 0x7fffu + ((v.u >> 16) & 1u);
  return (u16)(r >> 16);
}
__device__ __forceinline__ float bf2f(u16 h) {
  union { unsigned u; float f; } v; v.u = ((unsigned)h) << 16;
  return v.f;
}
__device__ __forceinline__ void gl_lds16(const u16* g, u16* l) {
  __builtin_amdgcn_global_load_lds(
      (const __attribute__((address_space(1))) unsigned int*)g,
      (__attribute__((address_space(3))) unsigned int*)l, 16, 0, 0);
}

// ---------------------------------------------------------------------------
// K0: convert x, w_qkv, w_proj f32 -> bf16 (one pass)
// ---------------------------------------------------------------------------
__global__ __launch_bounds__(256) void cvt_bf16_k(
    const float* __restrict__ x, const float* __restrict__ wq,
    const float* __restrict__ wp, u16* __restrict__ xb,
    u16* __restrict__ wqb, u16* __restrict__ wpb) {
  const size_t i = (size_t)blockIdx.x * 256 + threadIdx.x;  // 8-float chunk id
  const float* src; u16* dst; size_t off;
  if (i < 524288)       { src = x;  dst = xb;  off = i; }
  else if (i < 917504)  { src = wq; dst = wqb; off = i - 524288; }
  else                  { src = wp; dst = wpb; off = i - 917504; }
  const f32x4 a = ((const f32x4*)src)[off * 2];
  const f32x4 b = ((const f32x4*)src)[off * 2 + 1];
  u16x8 p;
#pragma unroll
  for (int e = 0; e < 4; ++e) { p[e] = f2bf(a[e]); p[e + 4] = f2bf(b[e]); }
  ((u16x8*)dst)[off] = p;
}

// ---------------------------------------------------------------------------
// K1: qkv = x @ w_qkv^T (bf16, global_load_lds staging, XCD-chunked grid).
// ---------------------------------------------------------------------------
__global__ __launch_bounds__(256) void qkv_gemm_mfma(
    const u16* __restrict__ xb, const u16* __restrict__ wb,
    u16* __restrict__ qb, u16* __restrict__ kb, u16* __restrict__ vb) {
  __shared__ u16 At[128 * 64];
  __shared__ u16 Bt[128 * 64];
  const int tid = threadIdx.x;
  // XCD-chunked: 768 blocks, XCD x gets 4 m-panels x 24 o-panels
  const int lin = blockIdx.y * 24 + blockIdx.x;
  const int swz = (lin & 7) * 96 + (lin >> 3);
  const int m0 = (swz / 24) * 128;
  const int o0 = (swz % 24) * 128;
  const int l = tid & 63, wv = tid >> 6;
  const int wm = (wv >> 1) * 64, wn = (wv & 1) * 64;
  const int lr = l & 15, lg = l >> 4;
  const int srow = l >> 3, scol = (l & 7) * 8;

  f32x4 acc[4][4];
#pragma unroll
  for (int i = 0; i < 4; ++i)
#pragma unroll
    for (int j = 0; j < 4; ++j) acc[i][j] = (f32x4){0.f, 0.f, 0.f, 0.f};

  for (int k0 = 0; k0 < 1024; k0 += 64) {
#pragma unroll
    for (int ii = 0; ii < 4; ++ii) {
      const int rbase = wv * 32 + ii * 8;
      gl_lds16(xb + (size_t)(m0 + rbase + srow) * 1024 + k0 + scol, At + rbase * 64);
      gl_lds16(wb + (size_t)(o0 + rbase + srow) * 1024 + k0 + scol, Bt + rbase * 64);
    }
    __syncthreads();
#pragma unroll
    for (int kg = 0; kg < 2; ++kg) {
      const int kbyte = (kg * 32 + 8 * lg) * 2;
      bf16x8 af[4], bfr[4];
#pragma unroll
      for (int mi = 0; mi < 4; ++mi)
        af[mi] = *(const bf16x8*)((const char*)At + (wm + mi * 16 + lr) * 128 + kbyte);
#pragma unroll
      for (int ni = 0; ni < 4; ++ni)
        bfr[ni] = *(const bf16x8*)((const char*)Bt + (wn + ni * 16 + lr) * 128 + kbyte);
#pragma unroll
      for (int mi = 0; mi < 4; ++mi)
#pragma unroll
        for (int ni = 0; ni < 4; ++ni)
          acc[mi][ni] = MFMA16(af[mi], bfr[ni], acc[mi][ni]);
    }
    __syncthreads();
  }

  const int o_base = o0 + wn;
  const int which = o_base >> 10;
  const int h = (o_base >> 6) & 15;
#pragma unroll
  for (int mi = 0; mi < 4; ++mi) {
#pragma unroll
    for (int ni = 0; ni < 4; ++ni) {
      const int d = ni * 16 + lr;
#pragma unroll
      for (int r = 0; r < 4; ++r) {
        int m = m0 + wm + mi * 16 + 4 * lg + r;
        int b_ = m >> 10, n_ = m & 1023;
        size_t dst = (((size_t)(b_ * 16 + h) * 1024) + n_) * 64 + d;
        float val = acc[mi][ni][r];
        if (which == 0)      qb[dst] = f2bf(val * 0.125f);
        else if (which == 1) kb[dst] = f2bf(val);
        else                 vb[dst] = f2bf(val);
      }
    }
  }
}

// ---------------------------------------------------------------------------
// K2: transpose v [bh][n][d] -> vT [bh][d][n]
// ---------------------------------------------------------------------------
__global__ __launch_bounds__(256) void vtrans_k(const u16* __restrict__ vb,
                                                u16* __restrict__ vt) {
  __shared__ u16 ts[64][72];
  const int bh = blockIdx.x >> 4;
  const int nt = (blockIdx.x & 15) * 64;
  const int t = threadIdx.x;
#pragma unroll
  for (int i = 0; i < 2; ++i) {
    int c = t * 2 + i, n = c >> 3, c8 = (c & 7) * 8;
    *(u16x8*)&ts[n][c8] = *(const u16x8*)&vb[((size_t)bh * 1024 + nt + n) * 64 + c8];
  }
  __syncthreads();
#pragma unroll
  for (int i = 0; i < 2; ++i) {
    int c = t * 2 + i, d = c >> 3, n8 = (c & 7) * 8;
    u16x8 p;
#pragma unroll
    for (int j = 0; j < 8; ++j) p[j] = ts[n8 + j][d];
    *(u16x8*)&vt[((size_t)bh * 64 + d) * 1024 + nt + n8] = p;
  }
}

// ---------------------------------------------------------------------------
// K3: rpe projections -> bf16 (+ compact kL0/kL62 rows).
// ---------------------------------------------------------------------------
__global__ __launch_bounds__(256) void rpe_proj_k(
    const u16* __restrict__ q, const u16* __restrict__ k,
    const float* __restrict__ tq, const float* __restrict__ tk,
    u16* __restrict__ qL, u16* __restrict__ kL,
    u16* __restrict__ kL0, u16* __restrict__ kL62) {
  __shared__ float tqs[64 * 63], tks[64 * 63];
  __shared__ u16 qr[16 * 64], kr[16 * 64];
  const int tid = threadIdx.x;
  const int r0 = blockIdx.x * 16;
  const int h = (r0 >> 10) & 15;
  for (int i = tid; i < 1008; i += 256) {
    ((f32x4*)tqs)[i] = ((const f32x4*)(tq + (size_t)h * 4032))[i];
    ((f32x4*)tks)[i] = ((const f32x4*)(tk + (size_t)h * 4032))[i];
  }
  for (int i = tid; i < 128; i += 256) {
    ((u16x8*)qr)[i] = ((const u16x8*)(q + (size_t)r0 * 64))[i];
    ((u16x8*)kr)[i] = ((const u16x8*)(k + (size_t)r0 * 64))[i];
  }
  __syncthreads();
  const int wv = tid >> 6, t = tid & 63;
  if (t < 63) {
#pragma unroll
    for (int rr = 0; rr < 4; ++rr) {
      const int row = wv * 4 + rr;
      float aq = 0.f, ak = 0.f;
#pragma unroll 8
      for (int d = 0; d < 64; ++d) {
        aq += bf2f(qr[row * 64 + d]) * tks[d * 63 + t];
        ak += bf2f(kr[row * 64 + d]) * tqs[d * 63 + t];
      }
      ak *= 0.125f;
      qL[(size_t)(r0 + row) * 63 + t] = f2bf(aq);
      kL[(size_t)(r0 + row) * 63 + t] = f2bf(ak);
      if (t == 0)  kL0[r0 + row] = f2bf(ak);
      if (t == 62) kL62[r0 + row] = f2bf(ak);
    }
  }
}

// ---------------------------------------------------------------------------
// K4: fused MFMA attention. Block = (b,h, 128 q-rows); 8 waves x 16 rows.
// K/V/kLs staging shared across the 128-row tile; 73.3KB LDS -> 2 blocks/CU,
// grid 512 = exactly 2/CU (no tail). T14 reg-prefetch; XCD-chunked grid.
// ---------------------------------------------------------------------------
__global__ __launch_bounds__(512, 4) void attn_mfma_k(
    const u16* __restrict__ qg, const u16* __restrict__ kgl,
    const u16* __restrict__ vtg, const u16* __restrict__ qLg,
    const u16* __restrict__ kLg, const u16* __restrict__ kL0g,
    const u16* __restrict__ kL62g, const float* __restrict__ tvg,
    u16* __restrict__ ao) {
  __shared__ u16 Kt[64 * 64];       // [j][d] swizzled          8K
  __shared__ u16 Vt[64 * 64];       // [d][j] swizzled          8K
  __shared__ u16 Pl[8 * 16 * 64];   // per-wave P bounce       16K
  __shared__ u16 qLs[128 * 63];     //                         16.1K
  __shared__ u16 kLs[64 * 63];      // band tile kL            8.06K
  __shared__ u16 segs[128 * 63];    //                         16.1K
  __shared__ u16 kl0t[64], kl62t[64];  // per-tile kL rows     256B

  const int tid = threadIdx.x;
  const int raw = blockIdx.x;
  const int bid = (raw & 7) * 64 + (raw >> 3);   // XCD-chunked (512 = 8*64)
  const int it = bid & 7;
  const int bh = bid >> 3;
  const int h = bh & 15;
  const int b_ = bh >> 4;
  const int i0 = it * 128;
  const int l = tid & 63, wv = tid >> 6;
  const int lr = l & 15, lg = l >> 4;
  const int iw0 = i0 + wv * 16;
  const size_t gbase = (size_t)bh * 1024;

  // ---- prologue ----
  for (int i = tid; i < 1008; i += 512) {
    ((u16x8*)segs)[i] = (u16x8){0, 0, 0, 0, 0, 0, 0, 0};
    ((u16x8*)qLs)[i] = ((const u16x8*)(qLg + (gbase + i0) * 63))[i];
  }
  bf16x8 qa[2];
  {
    const u16* qrow = qg + (gbase + iw0 + lr) * 64 + 8 * lg;
    qa[0] = *(const bf16x8*)(qrow);
    qa[1] = *(const bf16x8*)(qrow + 32);
  }
  const int st_row = tid >> 3, st_ch = tid & 7;
  const int dstb = st_row * 128 + ((st_ch * 16) ^ ((st_row & 7) << 4));
  u16x8 Kr, Vr, kLr, klr;
  {  // stage tile 0
    Kr = *(const u16x8*)(kgl + (gbase + st_row) * 64 + st_ch * 8);
    Vr = *(const u16x8*)(vtg + ((size_t)bh * 64 + st_row) * 1024 + st_ch * 8);
    *(u16x8*)((char*)Kt + dstb) = Kr;
    *(u16x8*)((char*)Vt + dstb) = Vr;
    if (i0 == 0 && tid < 504)
      ((u16x8*)kLs)[tid] = ((const u16x8*)(kLg + gbase * 63))[tid];
    if (tid < 8)       ((u16x8*)kl0t)[tid] = ((const u16x8*)(kL0g + gbase))[tid];
    else if (tid < 16) ((u16x8*)kl62t)[tid - 8] = ((const u16x8*)(kL62g + gbase))[tid - 8];
  }
  __syncthreads();

  float qL0r[4], qL62r[4];
#pragma unroll
  for (int r = 0; r < 4; ++r) {
    const int ir = wv * 16 + 4 * lg + r;
    qL0r[r] = bf2f(qLs[ir * 63 + 0]);
    qL62r[r] = bf2f(qLs[ir * 63 + 62]);
  }

  f32x4 pv[4];
#pragma unroll
  for (int db = 0; db < 4; ++db) pv[db] = (f32x4){0.f, 0.f, 0.f, 0.f};
  float lacc[4] = {0.f, 0.f, 0.f, 0.f}, racc[4] = {0.f, 0.f, 0.f, 0.f},
        rs[4] = {0.f, 0.f, 0.f, 0.f};

  for (int jt = 0; jt < 16; ++jt) {
    const int j0 = jt * 64;
    const int j0n = j0 + 64;
    const bool havenext = (jt < 15);
    const bool nband = havenext && (j0n >= i0 - 94) && (j0n <= i0 + 158);
    if (havenext) {  // T14: issue next tile's loads, write after barrier
      Kr = *(const u16x8*)(kgl + (gbase + j0n + st_row) * 64 + st_ch * 8);
      Vr = *(const u16x8*)(vtg + ((size_t)bh * 64 + st_row) * 1024 + j0n + st_ch * 8);
      if (nband && tid < 504)
        kLr = ((const u16x8*)(kLg + (gbase + j0n) * 63))[tid];
      if (tid < 8)       klr = ((const u16x8*)(kL0g + gbase + j0n))[tid];
      else if (tid < 16) klr = ((const u16x8*)(kL62g + gbase + j0n))[tid - 8];
    }

#pragma unroll
    for (int cb = 0; cb < 4; ++cb) {
      f32x4 sc = (f32x4){0.f, 0.f, 0.f, 0.f};
#pragma unroll
      for (int kgi = 0; kgi < 2; ++kgi) {
        const int row = cb * 16 + lr;
        bf16x8 kf = *(const bf16x8*)((const char*)Kt + row * 128 +
                                     (((kgi * 32 + 8 * lg) * 2) ^ ((row & 7) << 4)));
        sc = MFMA16(qa[kgi], kf, sc);
      }
      const int jlo = j0 + cb * 16;
      const int jcol = jlo + lr;
      const int jloc = cb * 16 + lr;     // 0..63 within tile
      const int pcolb = jloc * 2;
      if (jlo + 15 <= iw0 - 31) {        // fully left of this wave's band
        const float kl62 = bf2f(kl62t[jloc]);
#pragma unroll
        for (int r = 0; r < 4; ++r) {
          const float e = __expf(sc[r] + qL0r[r] + kl62);
          lacc[r] += e; rs[r] += e;
          const int prow = 4 * lg + r;
          *(u16*)((char*)Pl + wv * 2048 + prow * 128 + (pcolb ^ ((prow & 7) << 4))) = f2bf(e);
        }
      } else if (jlo >= iw0 + 46) {      // fully right
        const float kl0 = bf2f(kl0t[jloc]);
#pragma unroll
        for (int r = 0; r < 4; ++r) {
          const float e = __expf(sc[r] + qL62r[r] + kl0);
          racc[r] += e; rs[r] += e;
          const int prow = 4 * lg + r;
          *(u16*)((char*)Pl + wv * 2048 + prow * 128 + (pcolb ^ ((prow & 7) << 4))) = f2bf(e);
        }
      } else {                           // banded element-wise path
#pragma unroll
        for (int r = 0; r < 4; ++r) {
          const int irow = iw0 + 4 * lg + r;
          int rel = jcol - irow;
          rel = rel < -31 ? -31 : (rel > 31 ? 31 : rel);
          const int m = rel + 31;
          const float bias = bf2f(qLs[(irow - i0) * 63 + m]) +
                             bf2f(kLs[jloc * 63 + 62 - m]);
          const float e = __expf(sc[r] + bias);
          rs[r] += e;
          if (m == 0)       lacc[r] += e;
          else if (m == 62) racc[r] += e;
          else              segs[(irow - i0) * 63 + m] = f2bf(e);
          const int prow = 4 * lg + r;
          *(u16*)((char*)Pl + wv * 2048 + prow * 128 + (pcolb ^ ((prow & 7) << 4))) = f2bf(e);
        }
      }
    }
    // PV from wave-private Pl
#pragma unroll
    for (int db = 0; db < 4; ++db) {
#pragma unroll
      for (int kgi = 0; kgi < 2; ++kgi) {
        bf16x8 pa = *(const bf16x8*)((const char*)Pl + wv * 2048 + lr * 128 +
                                     (((kgi * 32 + 8 * lg) * 2) ^ ((lr & 7) << 4)));
        const int vrow = db * 16 + lr;
        bf16x8 vf = *(const bf16x8*)((const char*)Vt + vrow * 128 +
                                     (((kgi * 32 + 8 * lg) * 2) ^ ((vrow & 7) << 4)));
        pv[db] = MFMA16(pa, vf, pv[db]);
      }
    }
    __syncthreads();
    if (havenext) {
      *(u16x8*)((char*)Kt + dstb) = Kr;
      *(u16x8*)((char*)Vt + dstb) = Vr;
      if (nband && tid < 504) ((u16x8*)kLs)[tid] = kLr;
      if (tid < 8)       ((u16x8*)kl0t)[tid] = klr;
      else if (tid < 16) ((u16x8*)kl62t)[tid - 8] = klr;
    }
    __syncthreads();
  }

  // reduce rowsum / left / right across the 16 lanes sharing rows
#pragma unroll
  for (int r = 0; r < 4; ++r) {
#pragma unroll
    for (int m = 1; m < 16; m <<= 1) {
      rs[r] += __shfl_xor(rs[r], m);
      lacc[r] += __shfl_xor(lacc[r], m);
      racc[r] += __shfl_xor(racc[r], m);
    }
  }
  if (lr == 0) {
#pragma unroll
    for (int r = 0; r < 4; ++r) {
      const int ir = wv * 16 + 4 * lg + r;
      segs[ir * 63 + 0] = f2bf(lacc[r]);
      segs[ir * 63 + 62] = f2bf(racc[r]);
    }
  }
  __syncthreads();

  // epilogue: out = (PV + seg @ rpe_v[h]) / rowsum   (rowsum in regs)
#pragma unroll
  for (int db = 0; db < 4; ++db) {
    const int d = db * 16 + lr;
    float sadd[4] = {0.f, 0.f, 0.f, 0.f};
    for (int m = 0; m < 63; ++m) {
      const float tvv = tvg[((size_t)h * 63 + m) * 64 + d];
#pragma unroll
      for (int r = 0; r < 4; ++r)
        sadd[r] += bf2f(segs[(wv * 16 + 4 * lg + r) * 63 + m]) * tvv;
    }
#pragma unroll
    for (int r = 0; r < 4; ++r) {
      const int irow = i0 + wv * 16 + 4 * lg + r;
      const float val = (pv[db][r] + sadd[r]) / rs[r];
      ao[((size_t)(b_ * 1024) + irow) * 1024 + h * 64 + d] = f2bf(val);
    }
  }
}

// ---------------------------------------------------------------------------
// K5: out = ao(bf16) @ w_proj^T(bf16) + b_proj, f32 out.
// ---------------------------------------------------------------------------
__global__ __launch_bounds__(256) void proj_gemm_mfma(
    const u16* __restrict__ a, const u16* __restrict__ wpb,
    const float* __restrict__ bias, float* __restrict__ out) {
  __shared__ u16 At[128 * 64];
  __shared__ u16 Bt[128 * 64];
  const int tid = threadIdx.x;
  const int m0 = blockIdx.y * 128;
  const int o0 = blockIdx.x * 128;
  const int l = tid & 63, wv = tid >> 6;
  const int wm = (wv >> 1) * 64, wn = (wv & 1) * 64;
  const int lr = l & 15, lg = l >> 4;
  const int srow = l >> 3, scol = (l & 7) * 8;

  f32x4 acc[4][4];
#pragma unroll
  for (int i = 0; i < 4; ++i)
#pragma unroll
    for (int j = 0; j < 4; ++j) acc[i][j] = (f32x4){0.f, 0.f, 0.f, 0.f};

  for (int k0 = 0; k0 < 1024; k0 += 64) {
#pragma unroll
    for (int ii = 0; ii < 4; ++ii) {
      const int rbase = wv * 32 + ii * 8;
      gl_lds16(a + (size_t)(m0 + rbase + srow) * 1024 + k0 + scol, At + rbase * 64);
      gl_lds16(wpb + (size_t)(o0 + rbase + srow) * 1024 + k0 + scol, Bt + rbase * 64);
    }
    __syncthreads();
#pragma unroll
    for (int kg = 0; kg < 2; ++kg) {
      const int kbyte = (kg * 32 + 8 * lg) * 2;
      bf16x8 af[4], bfr[4];
#pragma unroll
      for (int mi = 0; mi < 4; ++mi)
        af[mi] = *(const bf16x8*)((const char*)At + (wm + mi * 16 + lr) * 128 + kbyte);
#pragma unroll
      for (int ni = 0; ni < 4; ++ni)
        bfr[ni] = *(const bf16x8*)((const char*)Bt + (wn + ni * 16 + lr) * 128 + kbyte);
#pragma unroll
      for (int mi = 0; mi < 4; ++mi)
#pragma unroll
        for (int ni = 0; ni < 4; ++ni)
          acc[mi][ni] = MFMA16(af[mi], bfr[ni], acc[mi][ni]);
    }
    __syncthreads();
  }
#pragma unroll
  for (int mi = 0; mi < 4; ++mi) {
#pragma unroll
    for (int ni = 0; ni < 4; ++ni) {
      const int o = o0 + wn + ni * 16 + lr;
      const float bv = bias[o];
#pragma unroll
      for (int r = 0; r < 4; ++r) {
        const int m = m0 + wm + mi * 16 + 4 * lg + r;
        out[(size_t)m * 1024 + o] = acc[mi][ni][r] + bv;
      }
    }
  }
}

// ---------------------------------------------------------------------------
extern "C" void kernel_launch(void* const* d_in, const int* in_sizes, int n_in,
                              void* d_out, int out_size, void* d_ws, size_t ws_size,
                              hipStream_t stream) {
  const float* x      = (const float*)d_in[0];
  const float* w_qkv  = (const float*)d_in[1];
  const float* w_proj = (const float*)d_in[2];
  const float* b_proj = (const float*)d_in[3];
  const float* tq     = (const float*)d_in[4];
  const float* tk     = (const float*)d_in[5];
  const float* tv     = (const float*)d_in[6];
  float* out = (float*)d_out;

  char* w8 = (char*)d_ws;
  u16* qb   = (u16*)(w8);                     // 8 MB  [bh][n][d]
  u16* kb   = (u16*)(w8 + (8ull << 20));      // 8 MB
  u16* vb   = (u16*)(w8 + (16ull << 20));     // 8 MB
  u16* vt   = (u16*)(w8 + (24ull << 20));     // 8 MB  [bh][d][n]
  u16* aob  = (u16*)(w8 + (32ull << 20));     // 8 MB  [b][n][c]
  u16* qL   = (u16*)(w8 + (40ull << 20));     // 8.26 MB [row][63] bf16
  u16* kL   = (u16*)(w8 + (49ull << 20));     // 8.26 MB
  u16* kL0  = (u16*)(w8 + (58ull << 20));     // 128 KB
  u16* kL62 = (u16*)(w8 + (59ull << 20));     // 128 KB
  u16* xb   = (u16*)(w8 + (60ull << 20));     // 8 MB
  u16* wqb  = (u16*)(w8 + (68ull << 20));     // 6 MB
  u16* wpb  = (u16*)(w8 + (74ull << 20));     // 2 MB

  hipLaunchKernelGGL(cvt_bf16_k, dim3(4096), dim3(256), 0, stream,
                     x, w_qkv, w_proj, xb, wqb, wpb);
  hipLaunchKernelGGL(qkv_gemm_mfma, dim3(24, 32), dim3(256), 0, stream,
                     xb, wqb, qb, kb, vb);
  hipLaunchKernelGGL(vtrans_k, dim3(1024), dim3(256), 0, stream, vb, vt);
  hipLaunchKernelGGL(rpe_proj_k, dim3(4096), dim3(256), 0, stream,
                     qb, kb, tq, tk, qL, kL, kL0, kL62);
  hipLaunchKernelGGL(attn_mfma_k, dim3(512), dim3(512), 0, stream,
                     qb, kb, vt, qL, kL, kL0, kL62, tv, aob);
  hipLaunchKernelGGL(proj_gemm_mfma, dim3(8, 32), dim3(256), 0, stream,
                     aob, wpb, b_proj, out);
}

// Round 10
// 327.473 us; speedup vs baseline: 1.0042x; 1.0042x over previous
//
#include <hip/hip_runtime.h>

typedef unsigned short u16;
typedef __attribute__((ext_vector_type(8))) short bf16x8;
typedef __attribute__((ext_vector_type(8))) unsigned short u16x8;
typedef __attribute__((ext_vector_type(4))) unsigned short u16x4;
typedef __attribute__((ext_vector_type(4))) float f32x4;

#define MFMA16(a, b, c) __builtin_amdgcn_mfma_f32_16x16x32_bf16(a, b, c, 0, 0, 0)

__device__ __forceinline__ u16 f2bf(float f) {
  union { float f; unsigned u; } v; v.f = f;
  unsigned r = v.u + 0x7fffu + ((v.u >> 16) & 1u);
  return (u16)(r >> 16);
}
__device__ __forceinline__ float bf2f(u16 h) {
  union { unsigned u; float f; } v; v.u = ((unsigned)h) << 16;
  return v.f;
}
__device__ __forceinline__ unsigned pk2bf(float a, float b) {  // round-half-up pack
  union { float f; unsigned u; } x, y; x.f = a; y.f = b;
  return ((x.u + 0x8000u) >> 16) | ((y.u + 0x8000u) & 0xffff0000u);
}
__device__ __forceinline__ void gl_lds16(const u16* g, u16* l) {
  __builtin_amdgcn_global_load_lds(
      (const __attribute__((address_space(1))) unsigned int*)g,
      (__attribute__((address_space(3))) unsigned int*)l, 16, 0, 0);
}

// ---------------------------------------------------------------------------
// K0: convert x, w_qkv, w_proj f32 -> bf16 (one pass)
// ---------------------------------------------------------------------------
__global__ __launch_bounds__(256) void cvt_bf16_k(
    const float* __restrict__ x, const float* __restrict__ wq,
    const float* __restrict__ wp, u16* __restrict__ xb,
    u16* __restrict__ wqb, u16* __restrict__ wpb) {
  const size_t i = (size_t)blockIdx.x * 256 + threadIdx.x;
  const float* src; u16* dst; size_t off;
  if (i < 524288)       { src = x;  dst = xb;  off = i; }
  else if (i < 917504)  { src = wq; dst = wqb; off = i - 524288; }
  else                  { src = wp; dst = wpb; off = i - 917504; }
  const f32x4 a = ((const f32x4*)src)[off * 2];
  const f32x4 b = ((const f32x4*)src)[off * 2 + 1];
  u16x8 p;
#pragma unroll
  for (int e = 0; e < 4; ++e) { p[e] = f2bf(a[e]); p[e + 4] = f2bf(b[e]); }
  ((u16x8*)dst)[off] = p;
}

// ---------------------------------------------------------------------------
// K1: qkv = x @ w_qkv^T (bf16, global_load_lds staging, XCD-chunked grid).
// ---------------------------------------------------------------------------
__global__ __launch_bounds__(256) void qkv_gemm_mfma(
    const u16* __restrict__ xb, const u16* __restrict__ wb,
    u16* __restrict__ qb, u16* __restrict__ kb, u16* __restrict__ vb) {
  __shared__ u16 At[128 * 64];
  __shared__ u16 Bt[128 * 64];
  const int tid = threadIdx.x;
  const int lin = blockIdx.y * 24 + blockIdx.x;
  const int swz = (lin & 7) * 96 + (lin >> 3);
  const int m0 = (swz / 24) * 128;
  const int o0 = (swz % 24) * 128;
  const int l = tid & 63, wv = tid >> 6;
  const int wm = (wv >> 1) * 64, wn = (wv & 1) * 64;
  const int lr = l & 15, lg = l >> 4;
  const int srow = l >> 3, scol = (l & 7) * 8;

  f32x4 acc[4][4];
#pragma unroll
  for (int i = 0; i < 4; ++i)
#pragma unroll
    for (int j = 0; j < 4; ++j) acc[i][j] = (f32x4){0.f, 0.f, 0.f, 0.f};

  for (int k0 = 0; k0 < 1024; k0 += 64) {
#pragma unroll
    for (int ii = 0; ii < 4; ++ii) {
      const int rbase = wv * 32 + ii * 8;
      gl_lds16(xb + (size_t)(m0 + rbase + srow) * 1024 + k0 + scol, At + rbase * 64);
      gl_lds16(wb + (size_t)(o0 + rbase + srow) * 1024 + k0 + scol, Bt + rbase * 64);
    }
    __syncthreads();
#pragma unroll
    for (int kg = 0; kg < 2; ++kg) {
      const int kbyte = (kg * 32 + 8 * lg) * 2;
      bf16x8 af[4], bfr[4];
#pragma unroll
      for (int mi = 0; mi < 4; ++mi)
        af[mi] = *(const bf16x8*)((const char*)At + (wm + mi * 16 + lr) * 128 + kbyte);
#pragma unroll
      for (int ni = 0; ni < 4; ++ni)
        bfr[ni] = *(const bf16x8*)((const char*)Bt + (wn + ni * 16 + lr) * 128 + kbyte);
#pragma unroll
      for (int mi = 0; mi < 4; ++mi)
#pragma unroll
        for (int ni = 0; ni < 4; ++ni)
          acc[mi][ni] = MFMA16(af[mi], bfr[ni], acc[mi][ni]);
    }
    __syncthreads();
  }

  const int o_base = o0 + wn;
  const int which = o_base >> 10;
  const int h = (o_base >> 6) & 15;
#pragma unroll
  for (int mi = 0; mi < 4; ++mi) {
#pragma unroll
    for (int ni = 0; ni < 4; ++ni) {
      const int d = ni * 16 + lr;
#pragma unroll
      for (int r = 0; r < 4; ++r) {
        int m = m0 + wm + mi * 16 + 4 * lg + r;
        int b_ = m >> 10, n_ = m & 1023;
        size_t dst = (((size_t)(b_ * 16 + h) * 1024) + n_) * 64 + d;
        float val = acc[mi][ni][r];
        if (which == 0)      qb[dst] = f2bf(val * 0.125f);
        else if (which == 1) kb[dst] = f2bf(val);
        else                 vb[dst] = f2bf(val);
      }
    }
  }
}

// ---------------------------------------------------------------------------
// K2: transpose v [bh][n][d] -> vT [bh][d][n]
// ---------------------------------------------------------------------------
__global__ __launch_bounds__(256) void vtrans_k(const u16* __restrict__ vb,
                                                u16* __restrict__ vt) {
  __shared__ u16 ts[64][72];
  const int bh = blockIdx.x >> 4;
  const int nt = (blockIdx.x & 15) * 64;
  const int t = threadIdx.x;
#pragma unroll
  for (int i = 0; i < 2; ++i) {
    int c = t * 2 + i, n = c >> 3, c8 = (c & 7) * 8;
    *(u16x8*)&ts[n][c8] = *(const u16x8*)&vb[((size_t)bh * 1024 + nt + n) * 64 + c8];
  }
  __syncthreads();
#pragma unroll
  for (int i = 0; i < 2; ++i) {
    int c = t * 2 + i, d = c >> 3, n8 = (c & 7) * 8;
    u16x8 p;
#pragma unroll
    for (int j = 0; j < 8; ++j) p[j] = ts[n8 + j][d];
    *(u16x8*)&vt[((size_t)bh * 64 + d) * 1024 + nt + n8] = p;
  }
}

// ---------------------------------------------------------------------------
// K3: rpe projections -> bf16 (+ compact kL0/kL62 rows).
// ---------------------------------------------------------------------------
__global__ __launch_bounds__(256) void rpe_proj_k(
    const u16* __restrict__ q, const u16* __restrict__ k,
    const float* __restrict__ tq, const float* __restrict__ tk,
    u16* __restrict__ qL, u16* __restrict__ kL,
    u16* __restrict__ kL0, u16* __restrict__ kL62) {
  __shared__ float tqs[64 * 63], tks[64 * 63];
  __shared__ u16 qr[16 * 64], kr[16 * 64];
  const int tid = threadIdx.x;
  const int r0 = blockIdx.x * 16;
  const int h = (r0 >> 10) & 15;
  for (int i = tid; i < 1008; i += 256) {
    ((f32x4*)tqs)[i] = ((const f32x4*)(tq + (size_t)h * 4032))[i];
    ((f32x4*)tks)[i] = ((const f32x4*)(tk + (size_t)h * 4032))[i];
  }
  for (int i = tid; i < 128; i += 256) {
    ((u16x8*)qr)[i] = ((const u16x8*)(q + (size_t)r0 * 64))[i];
    ((u16x8*)kr)[i] = ((const u16x8*)(k + (size_t)r0 * 64))[i];
  }
  __syncthreads();
  const int wv = tid >> 6, t = tid & 63;
  if (t < 63) {
#pragma unroll
    for (int rr = 0; rr < 4; ++rr) {
      const int row = wv * 4 + rr;
      float aq = 0.f, ak = 0.f;
#pragma unroll 8
      for (int d = 0; d < 64; ++d) {
        aq += bf2f(qr[row * 64 + d]) * tks[d * 63 + t];
        ak += bf2f(kr[row * 64 + d]) * tqs[d * 63 + t];
      }
      ak *= 0.125f;
      qL[(size_t)(r0 + row) * 63 + t] = f2bf(aq);
      kL[(size_t)(r0 + row) * 63 + t] = f2bf(ak);
      if (t == 0)  kL0[r0 + row] = f2bf(ak);
      if (t == 62) kL62[r0 + row] = f2bf(ak);
    }
  }
}

// ---------------------------------------------------------------------------
// K4: fused MFMA attention, swapped-QK^T + in-register P relayout (no P LDS).
// Block = (b,h, 128 q-rows); 8 waves x 16 rows; 57.5KB LDS.
// P^T frag: lane holds P[q=lr][j=cb*16+4*lg+r]; relayout to A-frag via 16 shfl.
// ---------------------------------------------------------------------------
__global__ __launch_bounds__(512, 4) void attn_mfma_k(
    const u16* __restrict__ qg, const u16* __restrict__ kgl,
    const u16* __restrict__ vtg, const u16* __restrict__ qLg,
    const u16* __restrict__ kLg, const u16* __restrict__ kL0g,
    const u16* __restrict__ kL62g, const float* __restrict__ tvg,
    u16* __restrict__ ao) {
  __shared__ u16 Kt[64 * 64];       // [j][d] swizzled          8K
  __shared__ u16 Vt[64 * 64];       // [d][j] swizzled          8K
  __shared__ u16 qLs[128 * 63];     //                         16.1K
  __shared__ u16 kLs[64 * 63];      // band tile kL            8.06K
  __shared__ u16 segs[128 * 63];    //                         16.1K
  __shared__ u16x4 kl0t4[16], kl62t4[16];  // per-tile kL rows 256B

  const int tid = threadIdx.x;
  const int raw = blockIdx.x;
  const int bid = (raw & 7) * 64 + (raw >> 3);   // XCD-chunked (512 = 8*64)
  const int it = bid & 7;
  const int bh = bid >> 3;
  const int h = bh & 15;
  const int b_ = bh >> 4;
  const int i0 = it * 128;
  const int l = tid & 63, wv = tid >> 6;
  const int lr = l & 15, lg = l >> 4;
  const int iw0 = i0 + wv * 16;
  const size_t gbase = (size_t)bh * 1024;

  // ---- prologue ----
  for (int i = tid; i < 1008; i += 512) {
    ((u16x8*)segs)[i] = (u16x8){0, 0, 0, 0, 0, 0, 0, 0};
    ((u16x8*)qLs)[i] = ((const u16x8*)(qLg + (gbase + i0) * 63))[i];
  }
  bf16x8 qa[2];
  {
    const u16* qrow = qg + (gbase + iw0 + lr) * 64 + 8 * lg;
    qa[0] = *(const bf16x8*)(qrow);
    qa[1] = *(const bf16x8*)(qrow + 32);
  }
  const int st_row = tid >> 3, st_ch = tid & 7;
  const int dstb = st_row * 128 + ((st_ch * 16) ^ ((st_row & 7) << 4));
  u16x8 Kr, Vr, kLr, klr;
  {  // stage tile 0
    Kr = *(const u16x8*)(kgl + (gbase + st_row) * 64 + st_ch * 8);
    Vr = *(const u16x8*)(vtg + ((size_t)bh * 64 + st_row) * 1024 + st_ch * 8);
    *(u16x8*)((char*)Kt + dstb) = Kr;
    *(u16x8*)((char*)Vt + dstb) = Vr;
    if (i0 == 0 && tid < 504)
      ((u16x8*)kLs)[tid] = ((const u16x8*)(kLg + gbase * 63))[tid];
    if (tid < 8)       ((u16x8*)kl0t4)[tid] = ((const u16x8*)(kL0g + gbase))[tid];
    else if (tid < 16) ((u16x8*)kl62t4)[tid - 8] = ((const u16x8*)(kL62g + gbase))[tid - 8];
  }
  __syncthreads();

  const float qL0v = bf2f(qLs[(wv * 16 + lr) * 63 + 0]);
  const float qL62v = bf2f(qLs[(wv * 16 + lr) * 63 + 62]);

  f32x4 pv[4];
#pragma unroll
  for (int db = 0; db < 4; ++db) pv[db] = (f32x4){0.f, 0.f, 0.f, 0.f};
  float lacc = 0.f, racc = 0.f, rs = 0.f;

  for (int jt = 0; jt < 16; ++jt) {
    const int j0 = jt * 64;
    const int j0n = j0 + 64;
    const bool havenext = (jt < 15);
    const bool nband = havenext && (j0n >= i0 - 94) && (j0n <= i0 + 158);
    if (havenext) {  // T14: issue next tile's loads, write after barrier
      Kr = *(const u16x8*)(kgl + (gbase + j0n + st_row) * 64 + st_ch * 8);
      Vr = *(const u16x8*)(vtg + ((size_t)bh * 64 + st_row) * 1024 + j0n + st_ch * 8);
      if (nband && tid < 504)
        kLr = ((const u16x8*)(kLg + (gbase + j0n) * 63))[tid];
      if (tid < 8)       klr = ((const u16x8*)(kL0g + gbase + j0n))[tid];
      else if (tid < 16) klr = ((const u16x8*)(kL62g + gbase + j0n))[tid - 8];
    }

    unsigned w[4][2];
#pragma unroll
    for (int cb = 0; cb < 4; ++cb) {
      f32x4 sc = (f32x4){0.f, 0.f, 0.f, 0.f};
#pragma unroll
      for (int kgi = 0; kgi < 2; ++kgi) {
        const int row = cb * 16 + lr;
        bf16x8 kf = *(const bf16x8*)((const char*)Kt + row * 128 +
                                     (((kgi * 32 + 8 * lg) * 2) ^ ((row & 7) << 4)));
        sc = MFMA16(kf, qa[kgi], sc);   // SWAPPED: lane holds P[q=lr][j=cb*16+4lg+r]
      }
      const int jlo = j0 + cb * 16;
      float ev[4];
      if (jlo + 15 <= iw0 - 31) {        // all pairs m==0
        const u16x4 kv = kl62t4[cb * 4 + lg];
#pragma unroll
        for (int r = 0; r < 4; ++r) {
          const float e = __expf(sc[r] + qL0v + bf2f(kv[r]));
          lacc += e; rs += e; ev[r] = e;
        }
      } else if (jlo >= iw0 + 46) {      // all pairs m==62
        const u16x4 kv = kl0t4[cb * 4 + lg];
#pragma unroll
        for (int r = 0; r < 4; ++r) {
          const float e = __expf(sc[r] + qL62v + bf2f(kv[r]));
          racc += e; rs += e; ev[r] = e;
        }
      } else {                           // banded element-wise path
#pragma unroll
        for (int r = 0; r < 4; ++r) {
          const int jloc = cb * 16 + 4 * lg + r;
          int rel = (j0 + jloc) - (iw0 + lr);
          rel = rel < -31 ? -31 : (rel > 31 ? 31 : rel);
          const int m = rel + 31;
          const float bias = bf2f(qLs[(wv * 16 + lr) * 63 + m]) +
                             bf2f(kLs[jloc * 63 + 62 - m]);
          const float e = __expf(sc[r] + bias);
          rs += e;
          if (m == 0)       lacc += e;
          else if (m == 62) racc += e;
          else              segs[(wv * 16 + lr) * 63 + m] = f2bf(e);
          ev[r] = e;
        }
      }
      w[cb][0] = pk2bf(ev[0], ev[1]);
      w[cb][1] = pk2bf(ev[2], ev[3]);
    }

    // in-register relayout: P^T frag -> PV A-frag (P[q=lr][j=kgi*32+8lg+e])
    unsigned pf0[4], pf1[4];
#pragma unroll
    for (int u = 0; u < 4; ++u) {
      const int s = (l & 15) | ((((lg & 1) * 2) + (u >> 1)) << 4);
      const unsigned a0 = (unsigned)__shfl((int)w[0][u & 1], s, 64);
      const unsigned b0 = (unsigned)__shfl((int)w[1][u & 1], s, 64);
      const unsigned a1 = (unsigned)__shfl((int)w[2][u & 1], s, 64);
      const unsigned b1 = (unsigned)__shfl((int)w[3][u & 1], s, 64);
      pf0[u] = (lg >> 1) ? b0 : a0;
      pf1[u] = (lg >> 1) ? b1 : a1;
    }
    union { unsigned u[4]; bf16x8 v; } pA0, pA1;
#pragma unroll
    for (int u = 0; u < 4; ++u) { pA0.u[u] = pf0[u]; pA1.u[u] = pf1[u]; }

    // PV: out[q at 4lg+reg][d at lr]
#pragma unroll
    for (int db = 0; db < 4; ++db) {
      const int vrow = db * 16 + lr;
      bf16x8 vf0 = *(const bf16x8*)((const char*)Vt + vrow * 128 +
                                    (((8 * lg) * 2) ^ ((vrow & 7) << 4)));
      bf16x8 vf1 = *(const bf16x8*)((const char*)Vt + vrow * 128 +
                                    (((32 + 8 * lg) * 2) ^ ((vrow & 7) << 4)));
      pv[db] = MFMA16(pA0.v, vf0, pv[db]);
      pv[db] = MFMA16(pA1.v, vf1, pv[db]);
    }
    __syncthreads();
    if (havenext) {
      *(u16x8*)((char*)Kt + dstb) = Kr;
      *(u16x8*)((char*)Vt + dstb) = Vr;
      if (nband && tid < 504) ((u16x8*)kLs)[tid] = kLr;
      if (tid < 8)       ((u16x8*)kl0t4)[tid] = klr;
      else if (tid < 16) ((u16x8*)kl62t4)[tid - 8] = klr;
    }
    __syncthreads();
  }

  // reduce rowsum / left / right over lg groups (q=lr fixed per lane)
  rs += __shfl_xor(rs, 16); rs += __shfl_xor(rs, 32);
  lacc += __shfl_xor(lacc, 16); lacc += __shfl_xor(lacc, 32);
  racc += __shfl_xor(racc, 16); racc += __shfl_xor(racc, 32);
  if (l < 16) {
    segs[(wv * 16 + l) * 63 + 0] = f2bf(lacc);
    segs[(wv * 16 + l) * 63 + 62] = f2bf(racc);
  }
  __syncthreads();
  float rsr[4];
#pragma unroll
  for (int r = 0; r < 4; ++r) rsr[r] = __shfl(rs, 4 * lg + r, 64);

  // epilogue: out = (PV + seg @ rpe_v[h]) / rowsum
#pragma unroll
  for (int db = 0; db < 4; ++db) {
    const int d = db * 16 + lr;
    float sadd[4] = {0.f, 0.f, 0.f, 0.f};
    for (int m = 0; m < 63; ++m) {
      const float tvv = tvg[((size_t)h * 63 + m) * 64 + d];
#pragma unroll
      for (int r = 0; r < 4; ++r)
        sadd[r] += bf2f(segs[(wv * 16 + 4 * lg + r) * 63 + m]) * tvv;
    }
#pragma unroll
    for (int r = 0; r < 4; ++r) {
      const int irow = i0 + wv * 16 + 4 * lg + r;
      const float val = (pv[db][r] + sadd[r]) / rsr[r];
      ao[((size_t)(b_ * 1024) + irow) * 1024 + h * 64 + d] = f2bf(val);
    }
  }
}

// ---------------------------------------------------------------------------
// K5: out = ao(bf16) @ w_proj^T(bf16) + b_proj, f32 out.
// ---------------------------------------------------------------------------
__global__ __launch_bounds__(256) void proj_gemm_mfma(
    const u16* __restrict__ a, const u16* __restrict__ wpb,
    const float* __restrict__ bias, float* __restrict__ out) {
  __shared__ u16 At[128 * 64];
  __shared__ u16 Bt[128 * 64];
  const int tid = threadIdx.x;
  const int m0 = blockIdx.y * 128;
  const int o0 = blockIdx.x * 128;
  const int l = tid & 63, wv = tid >> 6;
  const int wm = (wv >> 1) * 64, wn = (wv & 1) * 64;
  const int lr = l & 15, lg = l >> 4;
  const int srow = l >> 3, scol = (l & 7) * 8;

  f32x4 acc[4][4];
#pragma unroll
  for (int i = 0; i < 4; ++i)
#pragma unroll
    for (int j = 0; j < 4; ++j) acc[i][j] = (f32x4){0.f, 0.f, 0.f, 0.f};

  for (int k0 = 0; k0 < 1024; k0 += 64) {
#pragma unroll
    for (int ii = 0; ii < 4; ++ii) {
      const int rbase = wv * 32 + ii * 8;
      gl_lds16(a + (size_t)(m0 + rbase + srow) * 1024 + k0 + scol, At + rbase * 64);
      gl_lds16(wpb + (size_t)(o0 + rbase + srow) * 1024 + k0 + scol, Bt + rbase * 64);
    }
    __syncthreads();
#pragma unroll
    for (int kg = 0; kg < 2; ++kg) {
      const int kbyte = (kg * 32 + 8 * lg) * 2;
      bf16x8 af[4], bfr[4];
#pragma unroll
      for (int mi = 0; mi < 4; ++mi)
        af[mi] = *(const bf16x8*)((const char*)At + (wm + mi * 16 + lr) * 128 + kbyte);
#pragma unroll
      for (int ni = 0; ni < 4; ++ni)
        bfr[ni] = *(const bf16x8*)((const char*)Bt + (wn + ni * 16 + lr) * 128 + kbyte);
#pragma unroll
      for (int mi = 0; mi < 4; ++mi)
#pragma unroll
        for (int ni = 0; ni < 4; ++ni)
          acc[mi][ni] = MFMA16(af[mi], bfr[ni], acc[mi][ni]);
    }
    __syncthreads();
  }
#pragma unroll
  for (int mi = 0; mi < 4; ++mi) {
#pragma unroll
    for (int ni = 0; ni < 4; ++ni) {
      const int o = o0 + wn + ni * 16 + lr;
      const float bv = bias[o];
#pragma unroll
      for (int r = 0; r < 4; ++r) {
        const int m = m0 + wm + mi * 16 + 4 * lg + r;
        out[(size_t)m * 1024 + o] = acc[mi][ni][r] + bv;
      }
    }
  }
}

// ---------------------------------------------------------------------------
extern "C" void kernel_launch(void* const* d_in, const int* in_sizes, int n_in,
                              void* d_out, int out_size, void* d_ws, size_t ws_size,
                              hipStream_t stream) {
  const float* x      = (const float*)d_in[0];
  const float* w_qkv  = (const float*)d_in[1];
  const float* w_proj = (const float*)d_in[2];
  const float* b_proj = (const float*)d_in[3];
  const float* tq     = (const float*)d_in[4];
  const float* tk     = (const float*)d_in[5];
  const float* tv     = (const float*)d_in[6];
  float* out = (float*)d_out;

  char* w8 = (char*)d_ws;
  u16* qb   = (u16*)(w8);                     // 8 MB  [bh][n][d]
  u16* kb   = (u16*)(w8 + (8ull << 20));      // 8 MB
  u16* vb   = (u16*)(w8 + (16ull << 20));     // 8 MB
  u16* vt   = (u16*)(w8 + (24ull << 20));     // 8 MB  [bh][d][n]
  u16* aob  = (u16*)(w8 + (32ull << 20));     // 8 MB  [b][n][c]
  u16* qL   = (u16*)(w8 + (40ull << 20));     // 8.26 MB [row][63] bf16
  u16* kL   = (u16*)(w8 + (49ull << 20));     // 8.26 MB
  u16* kL0  = (u16*)(w8 + (58ull << 20));     // 128 KB
  u16* kL62 = (u16*)(w8 + (59ull << 20));     // 128 KB
  u16* xb   = (u16*)(w8 + (60ull << 20));     // 8 MB
  u16* wqb  = (u16*)(w8 + (68ull << 20));     // 6 MB
  u16* wpb  = (u16*)(w8 + (74ull << 20));     // 2 MB

  hipLaunchKernelGGL(cvt_bf16_k, dim3(4096), dim3(256), 0, stream,
                     x, w_qkv, w_proj, xb, wqb, wpb);
  hipLaunchKernelGGL(qkv_gemm_mfma, dim3(24, 32), dim3(256), 0, stream,
                     xb, wqb, qb, kb, vb);
  hipLaunchKernelGGL(vtrans_k, dim3(1024), dim3(256), 0, stream, vb, vt);
  hipLaunchKernelGGL(rpe_proj_k, dim3(4096), dim3(256), 0, stream,
                     qb, kb, tq, tk, qL, kL, kL0, kL62);
  hipLaunchKernelGGL(attn_mfma_k, dim3(512), dim3(512), 0, stream,
                     qb, kb, vt, qL, kL, kL0, kL62, tv, aob);
  hipLaunchKernelGGL(proj_gemm_mfma, dim3(8, 32), dim3(256), 0, stream,
                     aob, wpb, b_proj, out);
}